// Round 1
// baseline (245.137 us; speedup 1.0000x reference)
//
#include <hip/hip_runtime.h>

// Parametric LIF forward (spike output only).
// x: [B=64, T=64, N=8192] fp32.  out: same shape, values in {0,1}.
// Recurrence per (b,n):  u = last*sig + x[t];  s = (u >= th);
//                        last = (u + lamb*(u-last)) * (1-s)
//
// R3 history: f2 lanes + 1-deep register pipeline -> ~73.7us (3.6 TB/s),
// 58% of the 6.29 TB/s copy ceiling. Two residual issues:
//   (1) 8 B/lane VMEM (512 B/wave-instr) vs the 16 B/lane sweet spot all
//       peak-BW kernels on gfx950 use (m13 copy, the 6.7 TB/s fills).
//   (2) 1-deep prefetch: each stage ends in one bulk s_waitcnt for 8 loads
//       whose FIFO position is NEWER than the prior stage's stores -> the
//       wait drains store acks too, and all waves dip in lockstep.
// R4: float4 lanes + triple-buffered 2-stage-deep prefetch (UN=4).
//   - 16 B/lane loads/stores (1 KiB per wave-instr), half the VMEM instrs.
//   - loads for stage k are issued 2 stages early; when stage k waits on
//     them they are the OLDEST vmcnt entries, so the wait never drains any
//     store ack, and 8 loads (8 KiB/wave) stay in flight continuously.
//   - per-element arithmetic sequence identical to R3 (all *_rn split ops,
//     no FMA contraction) -> bitwise-identical spikes, absmax 0.
//
// Per-thread state: 4 leak registers (l0..l3), 3x4 f4 buffers (48 VGPR),
// ~80 VGPR total -> no occupancy pressure at 256 thr/block, grid 512
// (= 2 blocks/CU, 8 waves/CU, 64 KiB load bytes in flight per CU vs the
// ~10 KiB needed to cover ~900cy HBM latency at the per-CU BW share).

#define LIF_B 64
#define LIF_T 64
#define LIF_N 8192
#define NV4 (LIF_N / 4)        // float4s per row = 2048
#define UN 4                   // t-steps per pipeline stage
#define NSTAGE (LIF_T / UN)    // 16

typedef float f4 __attribute__((ext_vector_type(4)));

#define LIF_STEP(LREG, COMP)                                                   \
    {                                                                          \
        float u = __fadd_rn(__fmul_rn(LREG, sig), v.COMP);                     \
        float s = (u >= th) ? 1.0f : 0.0f;                                     \
        LREG = __fmul_rn(__fadd_rn(u, __fmul_rn(lamb, __fsub_rn(u, LREG))),    \
                         __fsub_rn(1.0f, s));                                  \
        sv.COMP = s;                                                           \
    }

__global__ __launch_bounds__(256) void lif_fwd_kernel(
    const f4* __restrict__ x,
    const float* __restrict__ tau_p,
    const float* __restrict__ lamb_p,
    const float* __restrict__ th_p,
    f4* __restrict__ out)
{
    const int tid = blockIdx.x * blockDim.x + threadIdx.x;   // 0 .. B*NV4-1
    const int b   = tid >> 11;                               // / NV4 (2048)
    const int n4  = tid & (NV4 - 1);

    const float sig  = 1.0f / (1.0f + expf(-tau_p[0]));      // 0.5 exact
    const float lamb = lamb_p[0];
    const float th   = th_p[0];

    float l0 = 0.0f, l1 = 0.0f, l2 = 0.0f, l3 = 0.0f;       // carried state
    const size_t base = (size_t)b * LIF_T * NV4 + n4;

    f4 cur[UN], mid[UN], nxt[UN];

    // Prologue: stages 0 and 1 in flight.
#pragma unroll
    for (int i = 0; i < UN; ++i)
        cur[i] = x[base + (size_t)i * NV4];
#pragma unroll
    for (int i = 0; i < UN; ++i)
        mid[i] = x[base + (size_t)(UN + i) * NV4];

#pragma unroll
    for (int k = 0; k < NSTAGE; ++k) {
        // 1) Prefetch stage k+2 FIRST. These land in the vmcnt FIFO ahead of
        //    this stage's stores; by the time stage k+2 consumes them they
        //    are the oldest entries, so its wait drains no store acks.
        if (k + 2 < NSTAGE) {
#pragma unroll
            for (int i = 0; i < UN; ++i)
                nxt[i] = x[base + (size_t)((k + 2) * UN + i) * NV4];
        }

        // 2) Compute + store stage k (cur was loaded 2 stages ago -> ready).
#pragma unroll
        for (int i = 0; i < UN; ++i) {
            f4 v = cur[i];
            f4 sv;
            LIF_STEP(l0, x)
            LIF_STEP(l1, y)
            LIF_STEP(l2, z)
            LIF_STEP(l3, w)
            __builtin_nontemporal_store(sv, &out[base + (size_t)(k * UN + i) * NV4]);
        }

        // 3) Rotate (pure register renames after full unroll).
#pragma unroll
        for (int i = 0; i < UN; ++i) {
            cur[i] = mid[i];
            mid[i] = nxt[i];
        }
    }
}

extern "C" void kernel_launch(void* const* d_in, const int* in_sizes, int n_in,
                              void* d_out, int out_size, void* d_ws, size_t ws_size,
                              hipStream_t stream) {
    (void)in_sizes; (void)n_in; (void)out_size; (void)d_ws; (void)ws_size;

    const f4*    x     = (const f4*)d_in[0];
    const float* tau_p = (const float*)d_in[1];
    const float* lamb  = (const float*)d_in[2];
    const float* th    = (const float*)d_in[3];
    f4*          out   = (f4*)d_out;

    const int total_threads = LIF_B * NV4;           // 131072
    const int block = 256;
    const int grid  = total_threads / block;         // 512

    lif_fwd_kernel<<<grid, block, 0, stream>>>(x, tau_p, lamb, th, out);
}

// Round 2
// 235.681 us; speedup vs baseline: 1.0401x; 1.0401x over previous
//
#include <hip/hip_runtime.h>

// Parametric LIF forward (spike output only).
// x: [B=64, T=64, N=8192] fp32.  out: same shape, values in {0,1}.
// Recurrence per (b,n):  u = last*sig + x[t];  s = (u >= th);
//                        last = (u + lamb*(u-last)) * (1-s)
//
// History:
//  R3: f2 lanes, UN=8, 1-deep reg pipeline, grid 1024 (16 waves/CU) -> 73.7us
//      (3.6 TB/s eff). Stage slack ~350cy vs ~900cy HBM latency -> ~50% stall.
//  R4: f4 + 2-deep + full unroll -> REGRESSED to ~88us. VGPR_Count=32 proves
//      the compiler collapsed the pipeline (2-deep f4 needs >=32 VGPR for
//      in-flight data alone); f4 also halved TLP to 8 waves/CU.
//  R5: back to the R3 shape (f2, UN=8, grid 1024) + 2-deep triple buffer with
//      the stage loop kept ROLLED (#pragma unroll 1). The rolled loop makes
//      each load's 2-iteration lifetime structural - the compiler cannot sink
//      loads to uses across iterations, so the R4 collapse is impossible.
//      Steady-state FIFO at the wait for loads(k): [loads(k) | stores(k-1),
//      loads(k+1), stores(k), loads(k+2)] -> vmcnt wait leaves 8 KiB/wave of
//      loads in flight and never drains a store ack. 2 stages of compute
//      (~700-800cy) cover most of the ~900cy miss latency.
// Arithmetic identical to R3 (all *_rn split ops, no FMA contraction) ->
// bitwise-identical spikes, absmax 0.

#define LIF_B 64
#define LIF_T 64
#define LIF_N 8192
#define NV2 (LIF_N / 2)        // float2s per row = 4096
#define UN 8                   // t-steps per pipeline stage
#define NSTAGE (LIF_T / UN)    // 8

typedef float f2 __attribute__((ext_vector_type(2)));

// Compute + store one stage of UN timesteps from buffer BUF at stage index KS.
#define LIF_STAGE(BUF, KS)                                                     \
    {                                                                          \
        _Pragma("unroll")                                                      \
        for (int i = 0; i < UN; ++i) {                                         \
            f2 v = BUF[i];                                                     \
            f2 sv;                                                             \
            {                                                                  \
                float u = __fadd_rn(__fmul_rn(lx, sig), v.x);                  \
                float s = (u >= th) ? 1.0f : 0.0f;                             \
                lx = __fmul_rn(                                                \
                    __fadd_rn(u, __fmul_rn(lamb, __fsub_rn(u, lx))),           \
                    __fsub_rn(1.0f, s));                                       \
                sv.x = s;                                                      \
            }                                                                  \
            {                                                                  \
                float u = __fadd_rn(__fmul_rn(ly, sig), v.y);                  \
                float s = (u >= th) ? 1.0f : 0.0f;                             \
                ly = __fmul_rn(                                                \
                    __fadd_rn(u, __fmul_rn(lamb, __fsub_rn(u, ly))),           \
                    __fsub_rn(1.0f, s));                                       \
                sv.y = s;                                                      \
            }                                                                  \
            __builtin_nontemporal_store(                                       \
                sv, &out[base + (size_t)((KS) * UN + i) * NV2]);               \
        }                                                                      \
    }

__global__ __launch_bounds__(256, 4) void lif_fwd_kernel(
    const f2* __restrict__ x,
    const float* __restrict__ tau_p,
    const float* __restrict__ lamb_p,
    const float* __restrict__ th_p,
    f2* __restrict__ out)
{
    const int tid = blockIdx.x * blockDim.x + threadIdx.x;   // 0 .. B*NV2-1
    const int b   = tid >> 12;                               // / NV2 (4096)
    const int n2  = tid & (NV2 - 1);

    const float sig  = 1.0f / (1.0f + expf(-tau_p[0]));      // 0.5 exact
    const float lamb = lamb_p[0];
    const float th   = th_p[0];

    float lx = 0.0f, ly = 0.0f;                              // carried state
    const size_t base = (size_t)b * LIF_T * NV2 + n2;

    f2 cur[UN], mid[UN], nxt[UN];

    // Prologue: stages 0 and 1 in flight / landed.
#pragma unroll
    for (int i = 0; i < UN; ++i)
        cur[i] = x[base + (size_t)i * NV2];
#pragma unroll
    for (int i = 0; i < UN; ++i)
        mid[i] = x[base + (size_t)(UN + i) * NV2];

    // Main loop: KEPT ROLLED so the 2-deep pipeline is structural.
#pragma unroll 1
    for (int k = 0; k < NSTAGE - 2; ++k) {
        // 1) Prefetch stage k+2 first (independent of cur -> issued before
        //    the compiler's vmcnt wait for cur's loads).
#pragma unroll
        for (int i = 0; i < UN; ++i)
            nxt[i] = x[base + (size_t)((k + 2) * UN + i) * NV2];

        // 2) Compute + store stage k (loaded 2 iterations ago).
        LIF_STAGE(cur, k)

        // 3) Rotate buffers (v_movs; ~64cy vs ~900cy stage wall).
#pragma unroll
        for (int i = 0; i < UN; ++i) {
            cur[i] = mid[i];
            mid[i] = nxt[i];
        }
    }

    // Epilogue: last two stages, no more prefetch.
    LIF_STAGE(cur, NSTAGE - 2)
    LIF_STAGE(mid, NSTAGE - 1)
}

extern "C" void kernel_launch(void* const* d_in, const int* in_sizes, int n_in,
                              void* d_out, int out_size, void* d_ws, size_t ws_size,
                              hipStream_t stream) {
    (void)in_sizes; (void)n_in; (void)out_size; (void)d_ws; (void)ws_size;

    const f2*    x     = (const f2*)d_in[0];
    const float* tau_p = (const float*)d_in[1];
    const float* lamb  = (const float*)d_in[2];
    const float* th    = (const float*)d_in[3];
    f2*          out   = (f2*)d_out;

    const int total_threads = LIF_B * NV2;           // 262144
    const int block = 256;
    const int grid  = total_threads / block;         // 1024
    lif_fwd_kernel<<<grid, block, 0, stream>>>(x, tau_p, lamb, th, out);
}